// Round 7
// baseline (1936.324 us; speedup 1.0000x reference)
//
#include <hip/hip_runtime.h>

typedef unsigned short us_t;
typedef unsigned int u32;
typedef unsigned long long u64;
typedef __attribute__((ext_vector_type(8))) short bf16x8;
typedef __attribute__((ext_vector_type(4))) float f32x4;

// Problem constants
constexpr int V = 4000, E = 512, H = 512, NB = 32, To = 128, Ti = 512;
constexpr int T_STEPS = 129;          // To + 1

// ws layout (float offsets)
constexpr size_t OFF_XPRE = 0;                                   // us [129][2048][32] bf16 (transposed)
constexpr size_t OFF_WQ   = OFF_XPRE + (size_t)129*65536/2;      // us [256 b][128 r][16 col][8]
constexpr size_t OFF_WXP  = OFF_WQ + (size_t)256*128*16*8/2;     // us [64 kb][2048 g][8]
constexpr size_t OFF_W1P  = OFF_WXP + (size_t)64*2048*8/2;       // us [128 kb][512 c][8]
constexpr size_t OFF_H0B  = OFF_W1P + (size_t)128*512*8/2;       // us [130][64 g8][32 n][8]
constexpr size_t OFF_H1B  = OFF_H0B + (size_t)130*16384/2;       // us [130][64][32][8]
constexpr size_t OFF_H1T  = OFF_H1B + (size_t)130*16384/2;       // u64 [130][32][260] tagged h1 transposed
constexpr size_t OFF_ATB  = OFF_H1T + (size_t)130*8320*2;        // us [130][64][32][8] bf16 attc
constexpr size_t OFF_CTX  = OFF_ATB + (size_t)130*16384/2;       // f [130][64][32][8] atomic acc
constexpr size_t OFF_MZ   = OFF_CTX + (size_t)130*16384;         // u64 [130][256]
constexpr size_t OFF_HID  = OFF_MZ + (size_t)130*256*2;          // us [4128][512] bf16 hidden
constexpr size_t OFF_W2P  = OFF_HID + (size_t)4128*512/2;        // us [64][4096][8] packed W2
constexpr size_t OFF_CPM  = OFF_W2P + (size_t)64*4096*8/2;       // f [4128][16]
constexpr size_t OFF_CPS  = OFF_CPM + (size_t)4128*16;
constexpr size_t OFF_TGT  = OFF_CPS + (size_t)4128*16;           // f [4128]
constexpr size_t OFF_FLG  = OFF_TGT + 4128;                      // u32 [256] dense flags

__device__ __forceinline__ float sigmf(float x) { return 1.0f / (1.0f + __expf(-x)); }
__device__ __forceinline__ float tanh_fast(float x) {
    float e = __expf(-2.0f * fabsf(x));
    float t = (1.0f - e) / (1.0f + e);
    return copysignf(t, x);
}
__device__ __forceinline__ float bfl(u32 u) { return __uint_as_float(u << 16); }
__device__ __forceinline__ float bfh(u32 u) { return __uint_as_float(u & 0xffff0000u); }
__device__ __forceinline__ us_t f2b(float x) {
    u32 u = __float_as_uint(x);
    return (us_t)((u + 0x7fffu + ((u >> 16) & 1u)) >> 16);
}
__device__ __forceinline__ uint4 cvt_pk8(float4 a, float4 c) {
    u32 w0, w1, w2, w3;
    asm("v_cvt_pk_bf16_f32 %0, %1, %2" : "=v"(w0) : "v"(a.x), "v"(a.y));
    asm("v_cvt_pk_bf16_f32 %0, %1, %2" : "=v"(w1) : "v"(a.z), "v"(a.w));
    asm("v_cvt_pk_bf16_f32 %0, %1, %2" : "=v"(w2) : "v"(c.x), "v"(c.y));
    asm("v_cvt_pk_bf16_f32 %0, %1, %2" : "=v"(w3) : "v"(c.z), "v"(c.w));
    uint4 pk = {w0, w1, w2, w3};
    return pk;
}
__device__ __forceinline__ u64 aload64(const u64* p) {
    return __hip_atomic_load(p, __ATOMIC_RELAXED, __HIP_MEMORY_SCOPE_AGENT);
}

// ---- grid sync: dense per-block epoch flags (2 epochs/step) ----
__device__ __forceinline__ void arrive(u32* flg, int b, int tid, u32 val) {
    __syncthreads();
    if (tid == 0)
        __hip_atomic_store(flg + b, val, __ATOMIC_RELAXED, __HIP_MEMORY_SCOPE_AGENT);
}
__device__ __forceinline__ void wait_all(u32* flg, u32 target, int tid) {
    if (tid < 128) {
        const u64* f8 = (const u64*)flg;
        bool done = false;
        for (;;) {
            if (!done) {
                u64 v = __hip_atomic_load(f8 + tid, __ATOMIC_RELAXED, __HIP_MEMORY_SCOPE_AGENT);
                done = ((u32)v >= target) && ((u32)(v >> 32) >= target);
            }
            if (__all((int)done)) break;
            __builtin_amdgcn_s_sleep(2);
        }
    }
    __syncthreads();
}

// ---------------- init: zero flag/tag/acc state every launch ----------------
__global__ __launch_bounds__(256) void k_init(float* ws) {
    int t0 = blockIdx.x * 256 + threadIdx.x;
    int nth = gridDim.x * 256;
    float4 z4 = {0.f, 0.f, 0.f, 0.f};
    float4* c4 = (float4*)(ws + OFF_CTX);
    for (int i = t0; i < 130 * 32 * 128; i += nth) c4[i] = z4;
    float4* m4 = (float4*)(ws + OFF_MZ);
    for (int i = t0; i < 130 * 128; i += nth) m4[i] = z4;
    float4* t14 = (float4*)(ws + OFF_H1T);
    for (int i = t0; i < 130 * 4160; i += nth) t14[i] = z4;   // tagged h1T (u64[130][8320])
    float4* h04 = (float4*)(ws + OFF_H0B);
    float4* h14 = (float4*)(ws + OFF_H1B);
    for (int i = t0; i < 2048; i += nth) { h04[i] = z4; h14[i] = z4; }
    u32* fl = (u32*)(ws + OFF_FLG);
    if (t0 < 256) fl[t0] = 0u;
}

// ---------------- merged weight pre-pack (Wq | Wx | W1 | W2) ----------------
__global__ __launch_bounds__(256) void k_pack(const float* __restrict__ W_ih0,
                                              const float* __restrict__ W_hh0,
                                              const float* __restrict__ W_ih1,
                                              const float* __restrict__ W_hh1,
                                              const float* __restrict__ W1,
                                              const float* __restrict__ W2,
                                              float* ws) {
    int blk = blockIdx.x, tid = threadIdx.x;
    if (blk < 16384) {                     // Wq: seq B tiles
        int p = blk * 256 + tid;
        int j = p & 7, col = (p >> 3) & 15, r = (p >> 7) & 127, b = p >> 14;
        int k = r * 8 + j;
        int cl = col & 7;
        int gRow = (cl >> 1) * 512 + b * 2 + (cl & 1);
        float v;
        if (col < 8)
            v = (k < 512) ? W_ih0[(size_t)gRow * 1024 + 512 + k]
                          : W_hh0[(size_t)gRow * 512 + (k - 512)];
        else
            v = (k < 512) ? W_ih1[(size_t)gRow * 512 + k]
                          : W_hh1[(size_t)gRow * 512 + (k - 512)];
        ((us_t*)(ws + OFF_WQ))[p] = f2b(v);
    } else if (blk < 20480) {              // Wxp[kb][g][j] = W_ih0[g][kb*8+j]
        int p = (blk - 16384) * 256 + tid;
        int j = p & 7, g = (p >> 3) & 2047, kb = p >> 14;
        ((us_t*)(ws + OFF_WXP))[p] = f2b(W_ih0[(size_t)g * 1024 + kb * 8 + j]);
    } else if (blk < 22528) {              // W1p[kb][c][j] = W1[c][kb*8+j]
        int p = (blk - 20480) * 256 + tid;
        int j = p & 7, c = (p >> 3) & 511, kb = p >> 12;
        ((us_t*)(ws + OFF_W1P))[p] = f2b(W1[(size_t)c * 1024 + kb * 8 + j]);
    } else {                               // W2p[kb][v][j]
        int p = (blk - 22528) * 256 + tid;
        int j = p & 7, v = (p >> 3) & 4095, kb = p >> 15;
        float x = (v < V) ? W2[(size_t)v * 512 + kb * 8 + j] : 0.0f;
        ((us_t*)(ws + OFF_W2P))[p] = f2b(x);
    }
}

// ---------------- X_pre GEMM via MFMA ----------------
__global__ __launch_bounds__(256) void k_xpre(const int* __restrict__ padded,
                                              const float* __restrict__ embedding,
                                              const us_t* __restrict__ Wxp,
                                              const float* __restrict__ b_ih0,
                                              const float* __restrict__ b_hh0,
                                              us_t* __restrict__ Xpre) {
    __shared__ __align__(16) us_t Ash[32 * 520];
    __shared__ int toks[32];
    const int t = blockIdx.x, gc = blockIdx.y, tid = threadIdx.x;
    if (tid < 32) toks[tid] = (t == 0) ? 1 : padded[tid * 128 + (t - 1)];
    __syncthreads();
#pragma unroll
    for (int i = 0; i < 16; ++i) {
        int f = tid + i * 256;
        int row = f >> 7, c4 = f & 127;
        float4 v = *(const float4*)(embedding + (size_t)toks[row] * 512 + c4 * 4);
        ushort4 o = {f2b(v.x), f2b(v.y), f2b(v.z), f2b(v.w)};
        *(ushort4*)(Ash + (size_t)row * 520 + c4 * 4) = o;
    }
    __syncthreads();
    const int w = tid >> 6, lane = tid & 63;
    const int quad = lane >> 4, l16 = lane & 15;
    f32x4 acc[2][4];
#pragma unroll
    for (int mt = 0; mt < 2; ++mt)
#pragma unroll
        for (int nt = 0; nt < 4; ++nt)
#pragma unroll
            for (int r = 0; r < 4; ++r) acc[mt][nt][r] = 0.0f;
    const int gbase = gc * 256 + w * 64;
    for (int ks = 0; ks < 16; ++ks) {
        bf16x8 a0 = *(const bf16x8*)(Ash + (size_t)(l16)      * 520 + ks * 32 + quad * 8);
        bf16x8 a1 = *(const bf16x8*)(Ash + (size_t)(16 + l16) * 520 + ks * 32 + quad * 8);
        const us_t* bp = Wxp + ((size_t)(ks * 4 + quad) * 2048 + gbase + l16) * 8;
#pragma unroll
        for (int nt = 0; nt < 4; ++nt) {
            bf16x8 bb = *(const bf16x8*)(bp + nt * 128);
            acc[0][nt] = __builtin_amdgcn_mfma_f32_16x16x32_bf16(a0, bb, acc[0][nt], 0, 0, 0);
            acc[1][nt] = __builtin_amdgcn_mfma_f32_16x16x32_bf16(a1, bb, acc[1][nt], 0, 0, 0);
        }
    }
    us_t* base = Xpre + (size_t)t * 65536;
#pragma unroll
    for (int nt = 0; nt < 4; ++nt) {
        int g = gc * 256 + w * 64 + nt * 16 + l16;
        float bias = b_ih0[g] + b_hh0[g];
#pragma unroll
        for (int mt = 0; mt < 2; ++mt) {
            ushort4 o = {f2b(acc[mt][nt][0] + bias), f2b(acc[mt][nt][1] + bias),
                         f2b(acc[mt][nt][2] + bias), f2b(acc[mt][nt][3] + bias)};
            *(ushort4*)(base + (size_t)g * 32 + mt * 16 + quad * 4) = o;
        }
    }
}

// ---------------- MFMA helper: one MFMA per wave per K-chunk ----------------
__device__ __forceinline__ void compute1(f32x4& a0, const us_t* __restrict__ Ab, int ktbase,
                                         int Mt, int kq, int l16, int quad,
                                         const us_t* __restrict__ lw) {
    bf16x8 av = *(const bf16x8*)(Ab + ((size_t)(kq * 4 + quad) * 32 + Mt * 16 + l16) * 8);
    bf16x8 bv = *(const bf16x8*)(lw + (((size_t)(ktbase + kq) * 4 + quad) * 16 + l16) * 8);
    a0 = __builtin_amdgcn_mfma_f32_16x16x32_bf16(av, bv, a0, 0, 0, 0);
}

// ---------------- gate reduction + nonlinearity + publish ----------------
__device__ __forceinline__ void tail_pub(f32x4 acc, int colbase,
                                         float g0, float g1, float g2, float g3,
                                         float& creg, u32* __restrict__ hOut32,
                                         u64* __restrict__ tagT, u32 tag,
                                         int b, int tid, float* red, float* gv) {
    const int l16 = tid & 15, quad = (tid >> 4) & 3, w = tid >> 6;
    const int Mt = w & 1, kq = w >> 1;
    const int cl = l16 - colbase;
    if ((unsigned)cl < 8u) {
        float4 v = {acc[0], acc[1], acc[2], acc[3]};
        *(float4*)&red[((size_t)(kq * 16 + Mt * 8 + cl)) * 20 + quad * 4] = v;
    }
    __syncthreads();
    if (tid < 256) {
        int row = tid >> 4, s = tid & 15;
        float g = 0.0f;
#pragma unroll
        for (int k2 = 0; k2 < 8; ++k2) g += red[((size_t)(k2 * 16 + row)) * 20 + s];
        gv[(row & 7) * 33 + (row >> 3) * 16 + s] = g;
    }
    __syncthreads();
    if (tid < 64) {
        int jl = tid >> 5, n = tid & 31;
        float gi = gv[jl * 33 + n]       + g0;
        float gf = gv[(2 + jl) * 33 + n] + g1;
        float gg = gv[(4 + jl) * 33 + n] + g2;
        float go = gv[(6 + jl) * 33 + n] + g3;
        float cn = sigmf(gf) * creg + sigmf(gi) * tanh_fast(gg);
        float hn = sigmf(go) * tanh_fast(cn);
        creg = cn;
        float hO = __shfl_xor(hn, 32);             // partner unit (jl^1), same sample
        if (jl == 0) {
            u32 pk = (u32)f2b(hn) | ((u32)f2b(hO) << 16);
            __hip_atomic_store(hOut32 + (((size_t)(b >> 2) * 32 + n) * 4 + (b & 3)), pk,
                               __ATOMIC_RELAXED, __HIP_MEMORY_SCOPE_AGENT);
            if (tagT) {
                u64 pk64 = ((u64)tag << 32) | (u64)pk;
                __hip_atomic_store(tagT + ((size_t)n * 260 + b), pk64,
                                   __ATOMIC_RELAXED, __HIP_MEMORY_SCOPE_AGENT);
            }
        }
    }
}

// ---------------- cooperative sequential kernel ----------------
// Ax retains h0(t+1) across ATTN (ATTN scratch lives in red_s) so P1's first
// half is 2 LDS-fed MFMAs with no global re-read.
__global__ __launch_bounds__(1024, 1) void k_seq(float* ws,
                                                 const float* __restrict__ enc,
                                                 const float* __restrict__ b_ih1,
                                                 const float* __restrict__ b_hh1) {
    __shared__ __align__(16) us_t lds_w[16384];      // 32 KB: Wq slice
    __shared__ __align__(16) us_t lds_e[64 * 552];   // 69 KB enc slice bf16, skewed
    __shared__ __align__(16) us_t Ax[2][8192];       // 2 x 16 KB X granule buffers
    __shared__ __align__(16) float red_s[8 * 16 * 20]; // K-reduce + ATTN scratch (2560 f)
    __shared__ __align__(16) float gv_s[272];

    const int b = blockIdx.x, tid = threadIdx.x;
    const int w = tid >> 6, l16 = tid & 15, quad = (tid >> 4) & 3;
    const int Mt = w & 1, kq = w >> 1;
    us_t* Ax0 = Ax[0];
    us_t* Ax1 = Ax[1];

    const us_t* XpreB = (const us_t*)(ws + OFF_XPRE);
    us_t* h0b = (us_t*)(ws + OFF_H0B);
    us_t* h1b = (us_t*)(ws + OFF_H1B);
    u64*  h1T = (u64*)(ws + OFF_H1T);
    us_t* atb = (us_t*)(ws + OFF_ATB);
    float* ctx = ws + OFF_CTX;
    u64*  mz  = (u64*)(ws + OFF_MZ);
    u32* flg = (u32*)(ws + OFF_FLG);

    const int an = b & 31, ac = b >> 5;   // XCD-local attention grouping

    float c0r = 0.0f, c1r = 0.0f;

    float bs0 = 0.f, bs1 = 0.f, bs2 = 0.f, bs3 = 0.f;
    if (tid < 64) {
        int j = b * 2 + (tid >> 5);
        bs0 = b_ih1[j] + b_hh1[j];
        bs1 = b_ih1[512 + j] + b_hh1[512 + j];
        bs2 = b_ih1[1024 + j] + b_hh1[1024 + j];
        bs3 = b_ih1[1536 + j] + b_hh1[1536 + j];
    }

    // ---- one-time LDS residency: weights + enc slice + h0(0) pre-stage ----
    {
        const uint4* wsrc = (const uint4*)((const us_t*)(ws + OFF_WQ) + (size_t)b * 16384);
        for (int f = tid; f < 2048; f += 1024) ((uint4*)lds_w)[f] = wsrc[f];
        const int ts0 = ac * 64;
        const float4* encn = (const float4*)(enc + ((size_t)an * 512 + ts0) * 512);
#pragma unroll
        for (int j = 0; j < 8; ++j) {
            int f = tid + j * 1024;
            int row = f >> 7, c4 = f & 127;
            float4 v = encn[(size_t)row * 128 + c4];
            ushort4 o;
            o.x = f2b(v.x); o.y = f2b(v.y); o.z = f2b(v.z); o.w = f2b(v.w);
            *(ushort4*)(lds_e + (size_t)row * 552 + (c4 >> 5) * 136 + (c4 & 31) * 4) = o;
        }
        // h0(0) = 0 (zeroed by k_init) into retained Ax
        uint4 a0 = ((const uint4*)h0b)[tid];
        uint4 a1 = ((const uint4*)(h0b + 8192))[tid];
        ((uint4*)Ax0)[tid] = a0;
        ((uint4*)Ax1)[tid] = a1;
    }
    __syncthreads();

    for (int t = 0; t < T_STEPS; ++t) {
        const u32 base = 2u * t;
        // ============ P1 half-A: h0(t) from RETAINED Ax (pure LDS) + Xpre prefetch ============
        float xg0 = 0.f, xg1 = 0.f, xg2 = 0.f, xg3 = 0.f;
        if (tid < 64) {
            const us_t* xp = XpreB + (size_t)t * 65536;
            int j = b * 2 + (tid >> 5), nn = tid & 31;
            xg0 = bfl(xp[(size_t)(0    + j) * 32 + nn]);
            xg1 = bfl(xp[(size_t)(512  + j) * 32 + nn]);
            xg2 = bfl(xp[(size_t)(1024 + j) * 32 + nn]);
            xg3 = bfl(xp[(size_t)(1536 + j) * 32 + nn]);
        }
        f32x4 acc;
#pragma unroll
        for (int r = 0; r < 4; ++r) acc[r] = 0.0f;
        compute1(acc, Ax0, 16, Mt, kq, l16, quad, lds_w);
        compute1(acc, Ax1, 24, Mt, kq, l16, quad, lds_w);
        wait_all(flg, base, tid);                  // attc(t) (normalized) ready
        // ============ P1 half-B: ctx(t) -> Ax, single barrier ============
        {
            const float* cts = ctx + (size_t)t * 16384;
            us_t* atbt = atb + (size_t)t * 16384;
            float4 a0 = *(const float4*)(cts + (size_t)tid * 8);
            float4 c0 = *(const float4*)(cts + (size_t)tid * 8 + 4);
            float4 a1 = *(const float4*)(cts + (size_t)(1024 + tid) * 8);
            float4 c1 = *(const float4*)(cts + (size_t)(1024 + tid) * 8 + 4);
            uint4 pk0 = cvt_pk8(a0, c0);
            *(uint4*)(Ax0 + (size_t)tid * 8) = pk0;
            if ((tid >> 3) == b) *(uint4*)(atbt + (size_t)tid * 8) = pk0;
            uint4 pk1 = cvt_pk8(a1, c1);
            *(uint4*)(Ax1 + (size_t)tid * 8) = pk1;
            {
                int gs = 1024 + tid;
                if ((gs >> 3) == b) *(uint4*)(atbt + (size_t)gs * 8) = pk1;
            }
            __syncthreads();
            compute1(acc, Ax0, 0, Mt, kq, l16, quad, lds_w);
            compute1(acc, Ax1, 8, Mt, kq, l16, quad, lds_w);
        }
        tail_pub(acc, 0, xg0, xg1, xg2, xg3, c0r,
                 (u32*)(h0b + (size_t)(t + 1) * 16384), nullptr, 0u, b, tid, red_s, gv_s);
        arrive(flg, b, tid, base + 1);
        // ============ P2 half-A: h1(t), single barrier (covers wait) ============
#pragma unroll
        for (int r = 0; r < 4; ++r) acc[r] = 0.0f;
        {
            const us_t* h1s = h1b + (size_t)t * 16384;
            uint4 a0 = ((const uint4*)h1s)[tid];
            uint4 a1 = ((const uint4*)(h1s + 8192))[tid];
            ((uint4*)Ax0)[tid] = a0;
            ((uint4*)Ax1)[tid] = a1;
            __syncthreads();
            compute1(acc, Ax0, 16, Mt, kq, l16, quad, lds_w);
            compute1(acc, Ax1, 24, Mt, kq, l16, quad, lds_w);
        }
        wait_all(flg, base + 1, tid);
        // ============ P2 half-B: h0(t+1) -> Ax (RETAINED through ATTN for next P1) ============
        {
            const us_t* h0n = h0b + (size_t)(t + 1) * 16384;
            uint4 a0 = ((const uint4*)h0n)[tid];
            uint4 a1 = ((const uint4*)(h0n + 8192))[tid];
            ((uint4*)Ax0)[tid] = a0;
            ((uint4*)Ax1)[tid] = a1;
            __syncthreads();
            compute1(acc, Ax0, 0, Mt, kq, l16, quad, lds_w);
            compute1(acc, Ax1, 8, Mt, kq, l16, quad, lds_w);
        }
        tail_pub(acc, 8, bs0, bs1, bs2, bs3, c1r,
                 (u32*)(h1b + (size_t)(t + 1) * 16384),
                 h1T + (size_t)(t + 1) * 8320, (u32)(t + 1), b, tid, red_s, gv_s);
        // NO arrive: ATTN polls tagged h1T directly
        // ============ ATTN: scratch in red_s (Ax untouched), tagged h1T poll ============
        {
            float* h_l = red_s;            // [16][33] = 528 f padded h
            float* scp = red_s + 528;      // [16][66] = 1056 f
            float* p_l = red_s + 1584;     // 64 f
            float* aux = red_s + 1648;     // 2 f
            if (tid < 256) {
                const u64* hp = h1T + (size_t)(t + 1) * 8320 + (size_t)an * 260 + tid;
                u64 v;
                for (;;) {
                    v = aload64(hp);
                    if ((u32)(v >> 32) == (u32)(t + 1)) break;
                    __builtin_amdgcn_s_sleep(2);
                }
                u32 hv = (u32)v;
                int idx = tid * 2;
                int kp = idx >> 5, off = idx & 31;
                h_l[kp * 33 + off]     = bfl(hv);
                h_l[kp * 33 + off + 1] = bfh(hv);
            }
            __syncthreads();
            {
                int ti = tid >> 4, kp = tid & 15;
                const us_t* er = lds_e + (size_t)ti * 552 + (kp >> 2) * 136 + (kp & 3) * 32;
                const float* hr = h_l + kp * 33;
                float s = 0.0f;
#pragma unroll
                for (int k8 = 0; k8 < 4; ++k8) {
                    uint4 u = *(const uint4*)(er + k8 * 8);
                    const float* h8 = hr + k8 * 8;
                    s += bfl(u.x) * h8[0] + bfh(u.x) * h8[1]
                       + bfl(u.y) * h8[2] + bfh(u.y) * h8[3]
                       + bfl(u.z) * h8[4] + bfh(u.z) * h8[5]
                       + bfl(u.w) * h8[6] + bfh(u.w) * h8[7];
                }
                scp[kp * 66 + ti] = s;
            }
            __syncthreads();
            if (tid < 64) {
                float sc = 0.0f;
#pragma unroll
                for (int kp = 0; kp < 16; ++kp) sc += scp[kp * 66 + tid];
                float m = sc;
                for (int o = 32; o; o >>= 1) m = fmaxf(m, __shfl_xor(m, o));
                float e = __expf(sc - m);
                float z = e;
                for (int o = 32; o; o >>= 1) z += __shfl_xor(z, o);
                p_l[tid] = e;
                if (tid == 0) {
                    aux[0] = m;
                    u64 pk = ((u64)__float_as_uint(m) << 32) | (u64)__float_as_uint(z);
                    __hip_atomic_store(mz + ((size_t)(t + 1) * 256 + an * 8 + ac), pk,
                                       __ATOMIC_RELAXED, __HIP_MEMORY_SCOPE_AGENT);
                }
            }
            __syncthreads();
            // unnormalized ctx contribution FIRST (overlaps sibling mz publishes)
            int d = tid >> 1, half = tid & 1;
            const us_t* eb = lds_e + (d >> 7) * 136 + (d & 127);
            float cv = 0.0f;
#pragma unroll 8
            for (int i = 0; i < 32; ++i) {
                int ti2 = half * 32 + i;
                cv += p_l[ti2] * bfl((u32)eb[(size_t)ti2 * 552]);
            }
            // mini-sync among the 8 chunk blocks of this sample -> global (M, Z)
            if (tid < 8) {
                u64 v;
                for (;;) {
                    v = aload64(mz + ((size_t)(t + 1) * 256 + an * 8 + tid));
                    if ((u32)v != 0u) break;
                    __builtin_amdgcn_s_sleep(1);
                }
                float mi = __uint_as_float((u32)(v >> 32));
                float zi = __uint_as_float((u32)v);
#pragma unroll
                for (int o = 1; o < 8; o <<= 1) {
                    float mo = __shfl_xor(mi, o);
                    float zo = __shfl_xor(zi, o);
                    float Mn = fmaxf(mi, mo);
                    zi = zi * __expf(mi - Mn) + zo * __expf(mo - Mn);
                    mi = Mn;
                }
                if (tid == 0)
                    aux[1] = __expf(aux[0] - mi) / zi;
            }
            __syncthreads();
            float scl = aux[1];
            float ov = __shfl_xor(cv, 1);
            if (half == 0) {
                int gs = (d >> 3) * 32 + an;
                float* dst = ctx + (size_t)(t + 1) * 16384 + (size_t)gs * 8 + (d & 7);
                __hip_atomic_fetch_add(dst, (cv + ov) * scl,
                                       __ATOMIC_RELAXED, __HIP_MEMORY_SCOPE_AGENT);
            }
        }
        arrive(flg, b, tid, base + 2);   // drains ctx atomics + this step's h publishes
    }
    // tail: materialize bf16 attc(129) for k_mlp (ctx already normalized)
    wait_all(flg, 2u * T_STEPS, tid);
    if (tid < 8) {
        int gs = b * 8 + tid;
        const float* s = ctx + (size_t)129 * 16384 + (size_t)gs * 8;
        float4 a = *(const float4*)s;
        float4 c = *(const float4*)(s + 4);
        uint4 pk = cvt_pk8(a, c);
        *(uint4*)(atb + (size_t)129 * 16384 + (size_t)gs * 8) = pk;
    }
}

// ---------------- MLP hidden GEMM via MFMA ----------------
__global__ __launch_bounds__(256) void k_mlp(const us_t* __restrict__ h1b,
                                             const us_t* __restrict__ atb,
                                             const us_t* __restrict__ W1p,
                                             const float* __restrict__ b1,
                                             us_t* __restrict__ hidb) {
    __shared__ __align__(16) us_t Ash[32 * 520];
    const int t = blockIdx.x, yc = blockIdx.y, tid = threadIdx.x;
    const int w = tid >> 6, lane = tid & 63;
    const int quad = lane >> 4, l16 = lane & 15;
    f32x4 acc[2][4];
#pragma unroll
    for (int mt = 0; mt < 2; ++mt)
#pragma unroll
        for (int nt = 0; nt < 4; ++nt)
#pragma unroll
            for (int r = 0; r < 4; ++r) acc[mt][nt][r] = 0.0f;
    const int cbase = yc * 256 + w * 64;
    for (int half = 0; half < 2; ++half) {
        const us_t* src = (half == 0) ? (h1b + (size_t)(t + 1) * 16384)
                                      : (atb + (size_t)t * 16384);
        __syncthreads();
#pragma unroll
        for (int i = 0; i < 8; ++i) {
            int f = tid + i * 256;
            int n = f & 31, g8 = f >> 5;
            uint4 v = *(const uint4*)(src + (size_t)f * 8);
            *(uint4*)(Ash + (size_t)n * 520 + g8 * 8) = v;
        }
        __syncthreads();
        for (int ks = 0; ks < 16; ++ks) {
            bf16x8 a0 = *(const bf16x8*)(Ash + (size_t)(l16)      * 520 + ks * 32 + quad * 8);
            bf16x8 a1 = *(const bf16x8*)(Ash + (size_t)(16 + l16) * 520 + ks * 32 + quad * 8);
            const us_t* bp = W1p + ((size_t)((half * 16 + ks) * 4 + quad) * 512 + cbase + l16) * 8;
#pragma unroll
            for (int nt = 0; nt < 4; ++nt) {
                bf16x8 bb = *(const bf16x8*)(bp + nt * 128);
                acc[0][nt] = __builtin_amdgcn_mfma_f32_16x16x32_bf16(a0, bb, acc[0][nt], 0, 0, 0);
                acc[1][nt] = __builtin_amdgcn_mfma_f32_16x16x32_bf16(a1, bb, acc[1][nt], 0, 0, 0);
            }
        }
    }
#pragma unroll
    for (int nt = 0; nt < 4; ++nt) {
        int c = yc * 256 + w * 64 + nt * 16 + l16;
        float bias = b1[c];
#pragma unroll
        for (int mt = 0; mt < 2; ++mt)
#pragma unroll
            for (int r = 0; r < 4; ++r) {
                int row = t * 32 + mt * 16 + quad * 4 + r;
                hidb[(size_t)row * 512 + c] = f2b(tanhf(acc[mt][nt][r] + bias));
            }
    }
}

// ---------------- MFMA logits + register-space logsumexp ----------------
__global__ __launch_bounds__(256) void k_ce(const us_t* __restrict__ hidb,
                                            const us_t* __restrict__ W2p,
                                            const float* __restrict__ b2,
                                            const int* __restrict__ padded,
                                            float* __restrict__ cpm, float* __restrict__ cps,
                                            float* __restrict__ tgt) {
    __shared__ __align__(16) us_t Ash[32 * 520];
    __shared__ float mredL[4 * 32];
    __shared__ float sredL[4 * 32];
    __shared__ float Mf[32];
    __shared__ int svst[32];
    const int t = blockIdx.x, vc = blockIdx.y, tid = threadIdx.x;
    if (tid < 32) svst[tid] = (t < 128) ? padded[tid * 128 + t] : 2;
    {
        const uint4* src = (const uint4*)(hidb + (size_t)t * 32 * 512);
#pragma unroll
        for (int i = 0; i < 8; ++i) {
            int f = tid + i * 256;
            uint4 v = src[f];
            *(uint4*)(Ash + (size_t)(f >> 6) * 520 + (f & 63) * 8) = v;
        }
    }
    __syncthreads();
    const int w = tid >> 6, lane = tid & 63;
    const int quad = lane >> 4, l16 = lane & 15;
    f32x4 acc[2][4];
#pragma unroll
    for (int mt = 0; mt < 2; ++mt)
#pragma unroll
        for (int nt = 0; nt < 4; ++nt)
#pragma unroll
            for (int r = 0; r < 4; ++r) acc[mt][nt][r] = 0.0f;
    const int vbase = vc * 256 + w * 64;
    for (int ks = 0; ks < 16; ++ks) {
        bf16x8 a0 = *(const bf16x8*)(Ash + (size_t)(l16)      * 520 + ks * 32 + quad * 8);
        bf16x8 a1 = *(const bf16x8*)(Ash + (size_t)(16 + l16) * 520 + ks * 32 + quad * 8);
        const us_t* bp = W2p + ((size_t)(ks * 4 + quad) * 4096 + vbase + l16) * 8;
#pragma unroll
        for (int nt = 0; nt < 4; ++nt) {
            bf16x8 bb = *(const bf16x8*)(bp + nt * 128);
            acc[0][nt] = __builtin_amdgcn_mfma_f32_16x16x32_bf16(a0, bb, acc[0][nt], 0, 0, 0);
            acc[1][nt] = __builtin_amdgcn_mfma_f32_16x16x32_bf16(a1, bb, acc[1][nt], 0, 0, 0);
        }
    }
    float bb4[4];
#pragma unroll
    for (int nt = 0; nt < 4; ++nt) {
        int vg = vbase + nt * 16 + l16;
        bb4[nt] = (vg < V) ? b2[vg] : -1e30f;
    }
    float lm[2][4];
#pragma unroll
    for (int mt = 0; mt < 2; ++mt)
#pragma unroll
        for (int r = 0; r < 4; ++r) {
            float m = acc[mt][0][r] + bb4[0];
            m = fmaxf(m, acc[mt][1][r] + bb4[1]);
            m = fmaxf(m, acc[mt][2][r] + bb4[2]);
            m = fmaxf(m, acc[mt][3][r] + bb4[3]);
            lm[mt][r] = m;
        }
#pragma unroll
    for (int o = 1; o < 16; o <<= 1)
#pragma unroll
        for (int mt = 0; mt < 2; ++mt)
#pragma unroll
            for (int r = 0; r < 4; ++r)
                lm[mt][r] = fmaxf(lm[mt][r], __shfl_xor(lm[mt][r], o));
    if (l16 == 0)
#pragma unroll
        for (int mt = 0; mt < 2; ++mt)
#pragma unroll
            for (int r = 0; r < 4; ++r)
                mredL[w * 32 + mt * 16 + quad * 4 + r] = lm[mt][r];
    __syncthreads();
    if (tid < 32)
        Mf[tid] = fmaxf(fmaxf(mredL[tid], mredL[32 + tid]),
                        fmaxf(mredL[64 + tid], mredL[96 + tid]));
    __syncthreads();
    float sm[2][4];
#pragma unroll
    for (int mt = 0; mt < 2; ++mt)
#pragma unroll
        for (int r = 0; r < 4; ++r) {
            int m = mt * 16 + quad * 4 + r;
            float M = Mf[m];
            int vsg = svst[m];
            float s = 0.0f;
#pragma unroll
            for (int nt = 0; nt < 4; ++nt) {
                float lv = acc[mt][nt][r] + bb4[nt];
                s += __expf(lv - M);
                if (vbase + nt * 16 + l16 == vsg) tgt[t * 32 + m] = lv;
            }
            sm[mt][r] = s;
        }
#pragma unroll
    for (int o = 1; o < 16; o <<= 1)
#pragma unroll
        for (int mt = 0; mt < 2; ++mt)
#pragma unroll
            for (int r = 0; r < 4; ++r)
                sm[mt][r] += __shfl_xor(sm[mt][r], o);
    if (l16 == 0)
#pragma unroll
        for (int mt = 0; mt < 2; ++mt)
#pragma unroll
            for (int r = 0; r < 4; ++r)
                sredL[w * 32 + mt * 16 + quad * 4 + r] = sm[mt][r];
    __syncthreads();
    if (tid < 32) {
        float S = sredL[tid] + sredL[32 + tid] + sredL[64 + tid] + sredL[96 + tid];
        int r = t * 32 + tid;
        cpm[(size_t)r * 16 + vc] = Mf[tid];
        cps[(size_t)r * 16 + vc] = S;
    }
}

// ---------------- final combine + CE reduction ----------------
__global__ __launch_bounds__(256) void k_final(const float* __restrict__ cpm,
                                               const float* __restrict__ cps,
                                               const float* __restrict__ tgt,
                                               float* __restrict__ out) {
    __shared__ float red[256];
    float local = 0.0f;
    for (int r = threadIdx.x; r < 4128; r += 256) {
        float M = -1e30f;
#pragma unroll
        for (int c = 0; c < 16; ++c) M = fmaxf(M, cpm[(size_t)r * 16 + c]);
        float S = 0.0f;
#pragma unroll
        for (int c = 0; c < 16; ++c) S += cps[(size_t)r * 16 + c] * __expf(cpm[(size_t)r * 16 + c] - M);
        local += (M + logf(S)) - tgt[r];
    }
    red[threadIdx.x] = local;
    __syncthreads();
    for (int o = 128; o; o >>= 1) {
        if (threadIdx.x < o) red[threadIdx.x] += red[threadIdx.x + o];
        __syncthreads();
    }
    if (threadIdx.x == 0) out[0] = red[0] * (128.0f / 4128.0f);
}

extern "C" void kernel_launch(void* const* d_in, const int* in_sizes, int n_in,
                              void* d_out, int out_size, void* d_ws, size_t ws_size,
                              hipStream_t stream) {
    const int*   padded = (const int*)d_in[0];
    const float* enc    = (const float*)d_in[1];
    const float* emb    = (const float*)d_in[2];
    const float* W_ih0  = (const float*)d_in[3];
    const float* b_ih0  = (const float*)d_in[4];
    const float* W_hh0  = (const float*)d_in[5];
    const float* b_hh0  = (const float*)d_in[6];
    const float* W_ih1  = (const float*)d_in[7];
    const float* b_ih1  = (const float*)d_in[8];
    const float* W_hh1  = (const float*)d_in[9];
    const float* b_hh1  = (const float*)d_in[10];
    const float* W1     = (const float*)d_in[11];
    const float* b1     = (const float*)d_in[12];
    const float* W2     = (const float*)d_in[13];
    const float* b2     = (const float*)d_in[14];
    float* ws  = (float*)d_ws;
    float* out = (float*)d_out;

    hipLaunchKernelGGL(k_init, dim3(640), dim3(256), 0, stream, ws);
    hipLaunchKernelGGL(k_pack, dim3(30720), dim3(256), 0, stream,
                       W_ih0, W_hh0, W_ih1, W_hh1, W1, W2, ws);
    hipLaunchKernelGGL(k_xpre, dim3(129, 8), dim3(256), 0, stream,
                       padded, emb, (const us_t*)(ws + OFF_WXP), b_ih0, b_hh0,
                       (us_t*)(ws + OFF_XPRE));
    {
        float* ws_a = ws;
        const float* enc_a = enc;
        const float* bia = b_ih1;
        const float* bib = b_hh1;
        void* args[] = {(void*)&ws_a, (void*)&enc_a, (void*)&bia, (void*)&bib};
        hipLaunchCooperativeKernel((void*)k_seq, dim3(256), dim3(1024), args, 0, stream);
    }
    hipLaunchKernelGGL(k_mlp, dim3(129, 2), dim3(256), 0, stream,
                       (const us_t*)(ws + OFF_H1B), (const us_t*)(ws + OFF_ATB),
                       (const us_t*)(ws + OFF_W1P), b1, (us_t*)(ws + OFF_HID));
    hipLaunchKernelGGL(k_ce, dim3(129, 16), dim3(256), 0, stream,
                       (const us_t*)(ws + OFF_HID), (const us_t*)(ws + OFF_W2P), b2, padded,
                       ws + OFF_CPM, ws + OFF_CPS, ws + OFF_TGT);
    hipLaunchKernelGGL(k_final, dim3(1), dim3(256), 0, stream,
                       ws + OFF_CPM, ws + OFF_CPS, ws + OFF_TGT, out);
}

// Round 8
// 1544.693 us; speedup vs baseline: 1.2535x; 1.2535x over previous
//
#include <hip/hip_runtime.h>

typedef unsigned short us_t;
typedef unsigned int u32;
typedef unsigned long long u64;
typedef __attribute__((ext_vector_type(8))) short bf16x8;
typedef __attribute__((ext_vector_type(4))) float f32x4;

// Problem constants
constexpr int V = 4000, E = 512, H = 512, NB = 32, To = 128, Ti = 512;
constexpr int T_STEPS = 129;          // To + 1

// ws layout (float offsets)
constexpr size_t OFF_XPRE = 0;                                   // us [129][2048][32] bf16 (transposed)
constexpr size_t OFF_WQ   = OFF_XPRE + (size_t)129*65536/2;      // us [256 b][128 r][16 col][8]
constexpr size_t OFF_WXP  = OFF_WQ + (size_t)256*128*16*8/2;     // us [64 kb][2048 g][8]
constexpr size_t OFF_W1P  = OFF_WXP + (size_t)64*2048*8/2;       // us [128 kb][512 c][8]
constexpr size_t OFF_H0B  = OFF_W1P + (size_t)128*512*8/2;       // us [130][64 g8][32 n][8]
constexpr size_t OFF_H1B  = OFF_H0B + (size_t)130*16384/2;       // us [130][64][32][8]
constexpr size_t OFF_H1T  = OFF_H1B + (size_t)130*16384/2;       // u64 [130][32][260] tagged h1 transposed
constexpr size_t OFF_ATB  = OFF_H1T + (size_t)130*8320*2;        // us [130][64][32][8] bf16 attc
constexpr size_t OFF_CTX  = OFF_ATB + (size_t)130*16384/2;       // f [130][64][32][8] atomic acc
constexpr size_t OFF_MZ   = OFF_CTX + (size_t)130*16384;         // u64 [130][256]
constexpr size_t OFF_HID  = OFF_MZ + (size_t)130*256*2;          // us [4128][512] bf16 hidden
constexpr size_t OFF_W2P  = OFF_HID + (size_t)4128*512/2;        // us [64][4096][8] packed W2
constexpr size_t OFF_CPM  = OFF_W2P + (size_t)64*4096*8/2;       // f [4128][16]
constexpr size_t OFF_CPS  = OFF_CPM + (size_t)4128*16;
constexpr size_t OFF_TGT  = OFF_CPS + (size_t)4128*16;           // f [4128]
constexpr size_t OFF_FLG  = OFF_TGT + 4128;                      // u32 [256] dense flags

__device__ __forceinline__ float sigmf(float x) { return 1.0f / (1.0f + __expf(-x)); }
__device__ __forceinline__ float tanh_fast(float x) {
    float e = __expf(-2.0f * fabsf(x));
    float t = (1.0f - e) / (1.0f + e);
    return copysignf(t, x);
}
__device__ __forceinline__ float bfl(u32 u) { return __uint_as_float(u << 16); }
__device__ __forceinline__ float bfh(u32 u) { return __uint_as_float(u & 0xffff0000u); }
__device__ __forceinline__ us_t f2b(float x) {
    u32 u = __float_as_uint(x);
    return (us_t)((u + 0x7fffu + ((u >> 16) & 1u)) >> 16);
}
__device__ __forceinline__ uint4 cvt_pk8(float4 a, float4 c) {
    u32 w0, w1, w2, w3;
    asm("v_cvt_pk_bf16_f32 %0, %1, %2" : "=v"(w0) : "v"(a.x), "v"(a.y));
    asm("v_cvt_pk_bf16_f32 %0, %1, %2" : "=v"(w1) : "v"(a.z), "v"(a.w));
    asm("v_cvt_pk_bf16_f32 %0, %1, %2" : "=v"(w2) : "v"(c.x), "v"(c.y));
    asm("v_cvt_pk_bf16_f32 %0, %1, %2" : "=v"(w3) : "v"(c.z), "v"(c.w));
    uint4 pk = {w0, w1, w2, w3};
    return pk;
}
__device__ __forceinline__ u64 aload64(const u64* p) {
    return __hip_atomic_load(p, __ATOMIC_RELAXED, __HIP_MEMORY_SCOPE_AGENT);
}

// ---- grid sync: dense per-block epoch flags (2 epochs/step) ----
__device__ __forceinline__ void arrive(u32* flg, int b, int tid, u32 val) {
    __syncthreads();
    if (tid == 0)
        __hip_atomic_store(flg + b, val, __ATOMIC_RELAXED, __HIP_MEMORY_SCOPE_AGENT);
}
__device__ __forceinline__ void wait_all(u32* flg, u32 target, int tid) {
    if (tid < 128) {
        const u64* f8 = (const u64*)flg;
        bool done = false;
        for (;;) {
            if (!done) {
                u64 v = __hip_atomic_load(f8 + tid, __ATOMIC_RELAXED, __HIP_MEMORY_SCOPE_AGENT);
                done = ((u32)v >= target) && ((u32)(v >> 32) >= target);
            }
            if (__all((int)done)) break;
            __builtin_amdgcn_s_sleep(2);
        }
    }
    __syncthreads();
}

// ---------------- init: zero flag/tag/acc state every launch ----------------
__global__ __launch_bounds__(256) void k_init(float* ws) {
    int t0 = blockIdx.x * 256 + threadIdx.x;
    int nth = gridDim.x * 256;
    float4 z4 = {0.f, 0.f, 0.f, 0.f};
    float4* c4 = (float4*)(ws + OFF_CTX);
    for (int i = t0; i < 130 * 32 * 128; i += nth) c4[i] = z4;
    float4* m4 = (float4*)(ws + OFF_MZ);
    for (int i = t0; i < 130 * 128; i += nth) m4[i] = z4;
    float4* t14 = (float4*)(ws + OFF_H1T);
    for (int i = t0; i < 130 * 4160; i += nth) t14[i] = z4;   // tagged h1T (u64[130][8320])
    float4* h04 = (float4*)(ws + OFF_H0B);
    float4* h14 = (float4*)(ws + OFF_H1B);
    for (int i = t0; i < 2048; i += nth) { h04[i] = z4; h14[i] = z4; }
    u32* fl = (u32*)(ws + OFF_FLG);
    if (t0 < 256) fl[t0] = 0u;
}

// ---------------- merged weight pre-pack (Wq | Wx | W1 | W2) ----------------
__global__ __launch_bounds__(256) void k_pack(const float* __restrict__ W_ih0,
                                              const float* __restrict__ W_hh0,
                                              const float* __restrict__ W_ih1,
                                              const float* __restrict__ W_hh1,
                                              const float* __restrict__ W1,
                                              const float* __restrict__ W2,
                                              float* ws) {
    int blk = blockIdx.x, tid = threadIdx.x;
    if (blk < 16384) {                     // Wq: seq B tiles
        int p = blk * 256 + tid;
        int j = p & 7, col = (p >> 3) & 15, r = (p >> 7) & 127, b = p >> 14;
        int k = r * 8 + j;
        int cl = col & 7;
        int gRow = (cl >> 1) * 512 + b * 2 + (cl & 1);
        float v;
        if (col < 8)
            v = (k < 512) ? W_ih0[(size_t)gRow * 1024 + 512 + k]
                          : W_hh0[(size_t)gRow * 512 + (k - 512)];
        else
            v = (k < 512) ? W_ih1[(size_t)gRow * 512 + k]
                          : W_hh1[(size_t)gRow * 512 + (k - 512)];
        ((us_t*)(ws + OFF_WQ))[p] = f2b(v);
    } else if (blk < 20480) {              // Wxp[kb][g][j] = W_ih0[g][kb*8+j]
        int p = (blk - 16384) * 256 + tid;
        int j = p & 7, g = (p >> 3) & 2047, kb = p >> 14;
        ((us_t*)(ws + OFF_WXP))[p] = f2b(W_ih0[(size_t)g * 1024 + kb * 8 + j]);
    } else if (blk < 22528) {              // W1p[kb][c][j] = W1[c][kb*8+j]
        int p = (blk - 20480) * 256 + tid;
        int j = p & 7, c = (p >> 3) & 511, kb = p >> 12;
        ((us_t*)(ws + OFF_W1P))[p] = f2b(W1[(size_t)c * 1024 + kb * 8 + j]);
    } else {                               // W2p[kb][v][j]
        int p = (blk - 22528) * 256 + tid;
        int j = p & 7, v = (p >> 3) & 4095, kb = p >> 15;
        float x = (v < V) ? W2[(size_t)v * 512 + kb * 8 + j] : 0.0f;
        ((us_t*)(ws + OFF_W2P))[p] = f2b(x);
    }
}

// ---------------- X_pre GEMM via MFMA ----------------
__global__ __launch_bounds__(256) void k_xpre(const int* __restrict__ padded,
                                              const float* __restrict__ embedding,
                                              const us_t* __restrict__ Wxp,
                                              const float* __restrict__ b_ih0,
                                              const float* __restrict__ b_hh0,
                                              us_t* __restrict__ Xpre) {
    __shared__ __align__(16) us_t Ash[32 * 520];
    __shared__ int toks[32];
    const int t = blockIdx.x, gc = blockIdx.y, tid = threadIdx.x;
    if (tid < 32) toks[tid] = (t == 0) ? 1 : padded[tid * 128 + (t - 1)];
    __syncthreads();
#pragma unroll
    for (int i = 0; i < 16; ++i) {
        int f = tid + i * 256;
        int row = f >> 7, c4 = f & 127;
        float4 v = *(const float4*)(embedding + (size_t)toks[row] * 512 + c4 * 4);
        ushort4 o = {f2b(v.x), f2b(v.y), f2b(v.z), f2b(v.w)};
        *(ushort4*)(Ash + (size_t)row * 520 + c4 * 4) = o;
    }
    __syncthreads();
    const int w = tid >> 6, lane = tid & 63;
    const int quad = lane >> 4, l16 = lane & 15;
    f32x4 acc[2][4];
#pragma unroll
    for (int mt = 0; mt < 2; ++mt)
#pragma unroll
        for (int nt = 0; nt < 4; ++nt)
#pragma unroll
            for (int r = 0; r < 4; ++r) acc[mt][nt][r] = 0.0f;
    const int gbase = gc * 256 + w * 64;
    for (int ks = 0; ks < 16; ++ks) {
        bf16x8 a0 = *(const bf16x8*)(Ash + (size_t)(l16)      * 520 + ks * 32 + quad * 8);
        bf16x8 a1 = *(const bf16x8*)(Ash + (size_t)(16 + l16) * 520 + ks * 32 + quad * 8);
        const us_t* bp = Wxp + ((size_t)(ks * 4 + quad) * 2048 + gbase + l16) * 8;
#pragma unroll
        for (int nt = 0; nt < 4; ++nt) {
            bf16x8 bb = *(const bf16x8*)(bp + nt * 128);
            acc[0][nt] = __builtin_amdgcn_mfma_f32_16x16x32_bf16(a0, bb, acc[0][nt], 0, 0, 0);
            acc[1][nt] = __builtin_amdgcn_mfma_f32_16x16x32_bf16(a1, bb, acc[1][nt], 0, 0, 0);
        }
    }
    us_t* base = Xpre + (size_t)t * 65536;
#pragma unroll
    for (int nt = 0; nt < 4; ++nt) {
        int g = gc * 256 + w * 64 + nt * 16 + l16;
        float bias = b_ih0[g] + b_hh0[g];
#pragma unroll
        for (int mt = 0; mt < 2; ++mt) {
            ushort4 o = {f2b(acc[mt][nt][0] + bias), f2b(acc[mt][nt][1] + bias),
                         f2b(acc[mt][nt][2] + bias), f2b(acc[mt][nt][3] + bias)};
            *(ushort4*)(base + (size_t)g * 32 + mt * 16 + quad * 4) = o;
        }
    }
}

// ---------------- MFMA helper: one MFMA per wave per K-chunk ----------------
__device__ __forceinline__ void compute1(f32x4& a0, const us_t* __restrict__ Ab, int ktbase,
                                         int Mt, int kq, int l16, int quad,
                                         const us_t* __restrict__ lw) {
    bf16x8 av = *(const bf16x8*)(Ab + ((size_t)(kq * 4 + quad) * 32 + Mt * 16 + l16) * 8);
    bf16x8 bv = *(const bf16x8*)(lw + (((size_t)(ktbase + kq) * 4 + quad) * 16 + l16) * 8);
    a0 = __builtin_amdgcn_mfma_f32_16x16x32_bf16(av, bv, a0, 0, 0, 0);
}

// ---------------- gate reduction + nonlinearity + publish ----------------
__device__ __forceinline__ void tail_pub(f32x4 acc, int colbase,
                                         float g0, float g1, float g2, float g3,
                                         float& creg, u32* __restrict__ hOut32,
                                         u64* __restrict__ tagT, u32 tag,
                                         int b, int tid, float* red, float* gv) {
    const int l16 = tid & 15, quad = (tid >> 4) & 3, w = tid >> 6;
    const int Mt = w & 1, kq = w >> 1;
    const int cl = l16 - colbase;
    if ((unsigned)cl < 8u) {
        float4 v = {acc[0], acc[1], acc[2], acc[3]};
        *(float4*)&red[((size_t)(kq * 16 + Mt * 8 + cl)) * 20 + quad * 4] = v;
    }
    __syncthreads();
    if (tid < 256) {
        int row = tid >> 4, s = tid & 15;
        float g = 0.0f;
#pragma unroll
        for (int k2 = 0; k2 < 8; ++k2) g += red[((size_t)(k2 * 16 + row)) * 20 + s];
        gv[(row & 7) * 33 + (row >> 3) * 16 + s] = g;
    }
    __syncthreads();
    if (tid < 64) {
        int jl = tid >> 5, n = tid & 31;
        float gi = gv[jl * 33 + n]       + g0;
        float gf = gv[(2 + jl) * 33 + n] + g1;
        float gg = gv[(4 + jl) * 33 + n] + g2;
        float go = gv[(6 + jl) * 33 + n] + g3;
        float cn = sigmf(gf) * creg + sigmf(gi) * tanh_fast(gg);
        float hn = sigmf(go) * tanh_fast(cn);
        creg = cn;
        float hO = __shfl_xor(hn, 32);             // partner unit (jl^1), same sample
        if (jl == 0) {
            u32 pk = (u32)f2b(hn) | ((u32)f2b(hO) << 16);
            __hip_atomic_store(hOut32 + (((size_t)(b >> 2) * 32 + n) * 4 + (b & 3)), pk,
                               __ATOMIC_RELAXED, __HIP_MEMORY_SCOPE_AGENT);
            if (tagT) {
                u64 pk64 = ((u64)tag << 32) | (u64)pk;
                __hip_atomic_store(tagT + ((size_t)n * 260 + b), pk64,
                                   __ATOMIC_RELAXED, __HIP_MEMORY_SCOPE_AGENT);
            }
        }
    }
}

// ---------------- cooperative sequential kernel (R6 structure, known-good) ----------------
__global__ __launch_bounds__(1024, 1) void k_seq(float* ws,
                                                 const float* __restrict__ enc,
                                                 const float* __restrict__ b_ih1,
                                                 const float* __restrict__ b_hh1) {
    __shared__ __align__(16) us_t lds_w[16384];      // 32 KB: Wq slice
    __shared__ __align__(16) us_t lds_e[64 * 552];   // 69 KB enc slice bf16, skewed
    __shared__ __align__(16) us_t Ax[2][8192];       // 2 x 16 KB X granule buffers
    __shared__ __align__(16) float red_s[8 * 16 * 20];
    __shared__ __align__(16) float gv_s[272];

    const int b = blockIdx.x, tid = threadIdx.x;
    const int w = tid >> 6, l16 = tid & 15, quad = (tid >> 4) & 3;
    const int Mt = w & 1, kq = w >> 1;
    us_t* Ax0 = Ax[0];
    us_t* Ax1 = Ax[1];

    const us_t* XpreB = (const us_t*)(ws + OFF_XPRE);
    us_t* h0b = (us_t*)(ws + OFF_H0B);
    us_t* h1b = (us_t*)(ws + OFF_H1B);
    u64*  h1T = (u64*)(ws + OFF_H1T);
    us_t* atb = (us_t*)(ws + OFF_ATB);
    float* ctx = ws + OFF_CTX;
    u64*  mz  = (u64*)(ws + OFF_MZ);
    u32* flg = (u32*)(ws + OFF_FLG);

    const int an = b & 31, ac = b >> 5;   // XCD-local attention grouping

    float c0r = 0.0f, c1r = 0.0f;

    float bs0 = 0.f, bs1 = 0.f, bs2 = 0.f, bs3 = 0.f;
    if (tid < 64) {
        int j = b * 2 + (tid >> 5);
        bs0 = b_ih1[j] + b_hh1[j];
        bs1 = b_ih1[512 + j] + b_hh1[512 + j];
        bs2 = b_ih1[1024 + j] + b_hh1[1024 + j];
        bs3 = b_ih1[1536 + j] + b_hh1[1536 + j];
    }

    // ---- one-time LDS residency: weights + enc slice ----
    {
        const uint4* wsrc = (const uint4*)((const us_t*)(ws + OFF_WQ) + (size_t)b * 16384);
        for (int f = tid; f < 2048; f += 1024) ((uint4*)lds_w)[f] = wsrc[f];
        const int ts0 = ac * 64;
        const float4* encn = (const float4*)(enc + ((size_t)an * 512 + ts0) * 512);
#pragma unroll
        for (int j = 0; j < 8; ++j) {
            int f = tid + j * 1024;
            int row = f >> 7, c4 = f & 127;
            float4 v = encn[(size_t)row * 128 + c4];
            ushort4 o;
            o.x = f2b(v.x); o.y = f2b(v.y); o.z = f2b(v.z); o.w = f2b(v.w);
            *(ushort4*)(lds_e + (size_t)row * 552 + (c4 >> 5) * 136 + (c4 & 31) * 4) = o;
        }
    }
    __syncthreads();

    for (int t = 0; t < T_STEPS; ++t) {
        const u32 base = 2u * t;
        // ============ P1: LSTM0, X = [attc(t) k0..511 | h0(t) k512..1023] ============
        float xg0 = 0.f, xg1 = 0.f, xg2 = 0.f, xg3 = 0.f;
        if (tid < 64) {
            const us_t* xp = XpreB + (size_t)t * 65536;
            int j = b * 2 + (tid >> 5), nn = tid & 31;
            xg0 = bfl(xp[(size_t)(0    + j) * 32 + nn]);
            xg1 = bfl(xp[(size_t)(512  + j) * 32 + nn]);
            xg2 = bfl(xp[(size_t)(1024 + j) * 32 + nn]);
            xg3 = bfl(xp[(size_t)(1536 + j) * 32 + nn]);
        }
        f32x4 acc;
#pragma unroll
        for (int r = 0; r < 4; ++r) acc[r] = 0.0f;
        {   // h0(t) half first (no barrier dependency, covers the attc wait): ktiles 16..31
            const us_t* h0s = h0b + (size_t)t * 16384;
            uint4 a0 = ((const uint4*)h0s)[tid];
            uint4 a1 = ((const uint4*)(h0s + 8192))[tid];
            ((uint4*)Ax0)[tid] = a0;
            __syncthreads();
            ((uint4*)Ax1)[tid] = a1;
            compute1(acc, Ax0, 16, Mt, kq, l16, quad, lds_w);
            __syncthreads();
            compute1(acc, Ax1, 24, Mt, kq, l16, quad, lds_w);
        }
        wait_all(flg, base, tid);                  // attc(t) (normalized) ready
        {
            const float* cts = ctx + (size_t)t * 16384;
            us_t* atbt = atb + (size_t)t * 16384;
            float4 a0 = *(const float4*)(cts + (size_t)tid * 8);
            float4 c0 = *(const float4*)(cts + (size_t)tid * 8 + 4);
            float4 a1 = *(const float4*)(cts + (size_t)(1024 + tid) * 8);
            float4 c1 = *(const float4*)(cts + (size_t)(1024 + tid) * 8 + 4);
            uint4 pk0 = cvt_pk8(a0, c0);
            *(uint4*)(Ax0 + (size_t)tid * 8) = pk0;
            if ((tid >> 3) == b) *(uint4*)(atbt + (size_t)tid * 8) = pk0;
            __syncthreads();
            uint4 pk1 = cvt_pk8(a1, c1);
            *(uint4*)(Ax1 + (size_t)tid * 8) = pk1;
            {
                int gs = 1024 + tid;
                if ((gs >> 3) == b) *(uint4*)(atbt + (size_t)gs * 8) = pk1;
            }
            compute1(acc, Ax0, 0, Mt, kq, l16, quad, lds_w);
            __syncthreads();
            compute1(acc, Ax1, 8, Mt, kq, l16, quad, lds_w);
        }
        tail_pub(acc, 0, xg0, xg1, xg2, xg3, c0r,
                 (u32*)(h0b + (size_t)(t + 1) * 16384), nullptr, 0u, b, tid, red_s, gv_s);
        arrive(flg, b, tid, base + 1);
        // ============ P2: LSTM1, X = [h0(t+1) k0..511 | h1(t) k512..1023] ============
#pragma unroll
        for (int r = 0; r < 4; ++r) acc[r] = 0.0f;
        {   // h1(t) half first: ktiles 16..31 (covers the h0(t+1) wait)
            const us_t* h1s = h1b + (size_t)t * 16384;
            uint4 a0 = ((const uint4*)h1s)[tid];
            uint4 a1 = ((const uint4*)(h1s + 8192))[tid];
            ((uint4*)Ax0)[tid] = a0;
            __syncthreads();
            ((uint4*)Ax1)[tid] = a1;
            compute1(acc, Ax0, 16, Mt, kq, l16, quad, lds_w);
            __syncthreads();
            compute1(acc, Ax1, 24, Mt, kq, l16, quad, lds_w);
        }
        wait_all(flg, base + 1, tid);
        {
            const us_t* h0n = h0b + (size_t)(t + 1) * 16384;
            uint4 a0 = ((const uint4*)h0n)[tid];
            uint4 a1 = ((const uint4*)(h0n + 8192))[tid];
            ((uint4*)Ax0)[tid] = a0;
            __syncthreads();
            ((uint4*)Ax1)[tid] = a1;
            compute1(acc, Ax0, 0, Mt, kq, l16, quad, lds_w);
            __syncthreads();
            compute1(acc, Ax1, 8, Mt, kq, l16, quad, lds_w);
        }
        tail_pub(acc, 8, bs0, bs1, bs2, bs3, c1r,
                 (u32*)(h1b + (size_t)(t + 1) * 16384),
                 h1T + (size_t)(t + 1) * 8320, (u32)(t + 1), b, tid, red_s, gv_s);
        // NO arrive: ATTN polls tagged h1T directly
        // ============ ATTN: tagged h1T poll (data IS the flag), cv overlaps mz sync ============
        {
            float* h_l = (float*)Ax0;      // [16][33] = 528 f padded h
            float* scp = h_l + 528;        // [16][66] = 1056 f
            float* p_l = h_l + 1584;       // 64 f
            float* aux = h_l + 1648;       // 2 f
            if (tid < 256) {
                const u64* hp = h1T + (size_t)(t + 1) * 8320 + (size_t)an * 260 + tid;
                u64 v;
                for (;;) {
                    v = aload64(hp);
                    if ((u32)(v >> 32) == (u32)(t + 1)) break;
                    __builtin_amdgcn_s_sleep(2);
                }
                u32 hv = (u32)v;
                int idx = tid * 2;
                int kp = idx >> 5, off = idx & 31;
                h_l[kp * 33 + off]     = bfl(hv);
                h_l[kp * 33 + off + 1] = bfh(hv);
            }
            __syncthreads();
            {
                int ti = tid >> 4, kp = tid & 15;
                const us_t* er = lds_e + (size_t)ti * 552 + (kp >> 2) * 136 + (kp & 3) * 32;
                const float* hr = h_l + kp * 33;
                float s = 0.0f;
#pragma unroll
                for (int k8 = 0; k8 < 4; ++k8) {
                    uint4 u = *(const uint4*)(er + k8 * 8);
                    const float* h8 = hr + k8 * 8;
                    s += bfl(u.x) * h8[0] + bfh(u.x) * h8[1]
                       + bfl(u.y) * h8[2] + bfh(u.y) * h8[3]
                       + bfl(u.z) * h8[4] + bfh(u.z) * h8[5]
                       + bfl(u.w) * h8[6] + bfh(u.w) * h8[7];
                }
                scp[kp * 66 + ti] = s;
            }
            __syncthreads();
            if (tid < 64) {
                float sc = 0.0f;
#pragma unroll
                for (int kp = 0; kp < 16; ++kp) sc += scp[kp * 66 + tid];
                float m = sc;
                for (int o = 32; o; o >>= 1) m = fmaxf(m, __shfl_xor(m, o));
                float e = __expf(sc - m);
                float z = e;
                for (int o = 32; o; o >>= 1) z += __shfl_xor(z, o);
                p_l[tid] = e;
                if (tid == 0) {
                    aux[0] = m;
                    u64 pk = ((u64)__float_as_uint(m) << 32) | (u64)__float_as_uint(z);
                    __hip_atomic_store(mz + ((size_t)(t + 1) * 256 + an * 8 + ac), pk,
                                       __ATOMIC_RELAXED, __HIP_MEMORY_SCOPE_AGENT);
                }
            }
            __syncthreads();
            // unnormalized ctx contribution FIRST (overlaps sibling mz publishes)
            int d = tid >> 1, half = tid & 1;
            const us_t* eb = lds_e + (d >> 7) * 136 + (d & 127);
            float cv = 0.0f;
#pragma unroll 8
            for (int i = 0; i < 32; ++i) {
                int ti2 = half * 32 + i;
                cv += p_l[ti2] * bfl((u32)eb[(size_t)ti2 * 552]);
            }
            // mini-sync among the 8 chunk blocks of this sample -> global (M, Z)
            if (tid < 8) {
                u64 v;
                for (;;) {
                    v = aload64(mz + ((size_t)(t + 1) * 256 + an * 8 + tid));
                    if ((u32)v != 0u) break;
                    __builtin_amdgcn_s_sleep(1);
                }
                float mi = __uint_as_float((u32)(v >> 32));
                float zi = __uint_as_float((u32)v);
#pragma unroll
                for (int o = 1; o < 8; o <<= 1) {
                    float mo = __shfl_xor(mi, o);
                    float zo = __shfl_xor(zi, o);
                    float Mn = fmaxf(mi, mo);
                    zi = zi * __expf(mi - Mn) + zo * __expf(mo - Mn);
                    mi = Mn;
                }
                if (tid == 0)
                    aux[1] = __expf(aux[0] - mi) / zi;
            }
            __syncthreads();
            float scl = aux[1];
            float ov = __shfl_xor(cv, 1);
            if (half == 0) {
                int gs = (d >> 3) * 32 + an;
                float* dst = ctx + (size_t)(t + 1) * 16384 + (size_t)gs * 8 + (d & 7);
                __hip_atomic_fetch_add(dst, (cv + ov) * scl,
                                       __ATOMIC_RELAXED, __HIP_MEMORY_SCOPE_AGENT);
            }
        }
        arrive(flg, b, tid, base + 2);   // drains ctx atomics + this step's h publishes
    }
    // tail: materialize bf16 attc(129) for k_mlp (ctx already normalized)
    wait_all(flg, 2u * T_STEPS, tid);
    if (tid < 8) {
        int gs = b * 8 + tid;
        const float* s = ctx + (size_t)129 * 16384 + (size_t)gs * 8;
        float4 a = *(const float4*)s;
        float4 c = *(const float4*)(s + 4);
        uint4 pk = cvt_pk8(a, c);
        *(uint4*)(atb + (size_t)129 * 16384 + (size_t)gs * 8) = pk;
    }
}

// ---------------- MLP hidden GEMM via MFMA ----------------
__global__ __launch_bounds__(256) void k_mlp(const us_t* __restrict__ h1b,
                                             const us_t* __restrict__ atb,
                                             const us_t* __restrict__ W1p,
                                             const float* __restrict__ b1,
                                             us_t* __restrict__ hidb) {
    __shared__ __align__(16) us_t Ash[32 * 520];
    const int t = blockIdx.x, yc = blockIdx.y, tid = threadIdx.x;
    const int w = tid >> 6, lane = tid & 63;
    const int quad = lane >> 4, l16 = lane & 15;
    f32x4 acc[2][4];
#pragma unroll
    for (int mt = 0; mt < 2; ++mt)
#pragma unroll
        for (int nt = 0; nt < 4; ++nt)
#pragma unroll
            for (int r = 0; r < 4; ++r) acc[mt][nt][r] = 0.0f;
    const int cbase = yc * 256 + w * 64;
    for (int half = 0; half < 2; ++half) {
        const us_t* src = (half == 0) ? (h1b + (size_t)(t + 1) * 16384)
                                      : (atb + (size_t)t * 16384);
        __syncthreads();
#pragma unroll
        for (int i = 0; i < 8; ++i) {
            int f = tid + i * 256;
            int n = f & 31, g8 = f >> 5;
            uint4 v = *(const uint4*)(src + (size_t)f * 8);
            *(uint4*)(Ash + (size_t)n * 520 + g8 * 8) = v;
        }
        __syncthreads();
        for (int ks = 0; ks < 16; ++ks) {
            bf16x8 a0 = *(const bf16x8*)(Ash + (size_t)(l16)      * 520 + ks * 32 + quad * 8);
            bf16x8 a1 = *(const bf16x8*)(Ash + (size_t)(16 + l16) * 520 + ks * 32 + quad * 8);
            const us_t* bp = W1p + ((size_t)((half * 16 + ks) * 4 + quad) * 512 + cbase + l16) * 8;
#pragma unroll
            for (int nt = 0; nt < 4; ++nt) {
                bf16x8 bb = *(const bf16x8*)(bp + nt * 128);
                acc[0][nt] = __builtin_amdgcn_mfma_f32_16x16x32_bf16(a0, bb, acc[0][nt], 0, 0, 0);
                acc[1][nt] = __builtin_amdgcn_mfma_f32_16x16x32_bf16(a1, bb, acc[1][nt], 0, 0, 0);
            }
        }
    }
#pragma unroll
    for (int nt = 0; nt < 4; ++nt) {
        int c = yc * 256 + w * 64 + nt * 16 + l16;
        float bias = b1[c];
#pragma unroll
        for (int mt = 0; mt < 2; ++mt)
#pragma unroll
            for (int r = 0; r < 4; ++r) {
                int row = t * 32 + mt * 16 + quad * 4 + r;
                hidb[(size_t)row * 512 + c] = f2b(tanhf(acc[mt][nt][r] + bias));
            }
    }
}

// ---------------- MFMA logits + register logsumexp, M=64 tile (halves W2p traffic) ----------------
__global__ __launch_bounds__(256) void k_ce(const us_t* __restrict__ hidb,
                                            const us_t* __restrict__ W2p,
                                            const float* __restrict__ b2,
                                            const int* __restrict__ padded,
                                            float* __restrict__ cpm, float* __restrict__ cps,
                                            float* __restrict__ tgt) {
    __shared__ __align__(16) us_t Ash[64 * 520];
    __shared__ float mredL[4 * 64];
    __shared__ float sredL[4 * 64];
    __shared__ float Mf[64];
    __shared__ int svst[64];
    const int tb = blockIdx.x, vc = blockIdx.y, tid = threadIdx.x;
    const int row0 = tb * 64;
    if (tid < 64) {
        int row = row0 + tid;
        int ts = row >> 5, n = row & 31;
        svst[tid] = (row < 4128) ? ((ts < 128) ? padded[n * 128 + ts] : 2) : -1;
    }
    {
        const uint4* src = (const uint4*)(hidb + (size_t)row0 * 512);
        uint4 z; z.x = 0u; z.y = 0u; z.z = 0u; z.w = 0u;
#pragma unroll
        for (int i = 0; i < 16; ++i) {
            int f = tid + i * 256;          // 4096 uint4 = 64 rows x 64 chunks
            int row = f >> 6, c8 = f & 63;
            uint4 v = (row0 + row < 4128) ? src[f] : z;
            *(uint4*)(Ash + (size_t)row * 520 + c8 * 8) = v;
        }
    }
    __syncthreads();
    const int w = tid >> 6, lane = tid & 63;
    const int quad = lane >> 4, l16 = lane & 15;
    f32x4 acc[4][4];
#pragma unroll
    for (int mt = 0; mt < 4; ++mt)
#pragma unroll
        for (int nt = 0; nt < 4; ++nt)
#pragma unroll
            for (int r = 0; r < 4; ++r) acc[mt][nt][r] = 0.0f;
    const int vbase = vc * 256 + w * 64;
    for (int ks = 0; ks < 16; ++ks) {
        bf16x8 a0 = *(const bf16x8*)(Ash + (size_t)(l16)      * 520 + ks * 32 + quad * 8);
        bf16x8 a1 = *(const bf16x8*)(Ash + (size_t)(16 + l16) * 520 + ks * 32 + quad * 8);
        bf16x8 a2 = *(const bf16x8*)(Ash + (size_t)(32 + l16) * 520 + ks * 32 + quad * 8);
        bf16x8 a3 = *(const bf16x8*)(Ash + (size_t)(48 + l16) * 520 + ks * 32 + quad * 8);
        const us_t* bp = W2p + ((size_t)(ks * 4 + quad) * 4096 + vbase + l16) * 8;
#pragma unroll
        for (int nt = 0; nt < 4; ++nt) {
            bf16x8 bb = *(const bf16x8*)(bp + nt * 128);
            acc[0][nt] = __builtin_amdgcn_mfma_f32_16x16x32_bf16(a0, bb, acc[0][nt], 0, 0, 0);
            acc[1][nt] = __builtin_amdgcn_mfma_f32_16x16x32_bf16(a1, bb, acc[1][nt], 0, 0, 0);
            acc[2][nt] = __builtin_amdgcn_mfma_f32_16x16x32_bf16(a2, bb, acc[2][nt], 0, 0, 0);
            acc[3][nt] = __builtin_amdgcn_mfma_f32_16x16x32_bf16(a3, bb, acc[3][nt], 0, 0, 0);
        }
    }
    float bb4[4];
#pragma unroll
    for (int nt = 0; nt < 4; ++nt) {
        int vg = vbase + nt * 16 + l16;
        bb4[nt] = (vg < V) ? b2[vg] : -1e30f;
    }
    // per-row max over this thread's 4 vocab, then over the 16 vocab lanes
    float lm[4][4];
#pragma unroll
    for (int mt = 0; mt < 4; ++mt)
#pragma unroll
        for (int r = 0; r < 4; ++r) {
            float m = acc[mt][0][r] + bb4[0];
            m = fmaxf(m, acc[mt][1][r] + bb4[1]);
            m = fmaxf(m, acc[mt][2][r] + bb4[2]);
            m = fmaxf(m, acc[mt][3][r] + bb4[3]);
            lm[mt][r] = m;
        }
#pragma unroll
    for (int o = 1; o < 16; o <<= 1)
#pragma unroll
        for (int mt = 0; mt < 4; ++mt)
#pragma unroll
            for (int r = 0; r < 4; ++r)
                lm[mt][r] = fmaxf(lm[mt][r], __shfl_xor(lm[mt][r], o));
    if (l16 == 0)
#pragma unroll
        for (int mt = 0; mt < 4; ++mt)
#pragma unroll
            for (int r = 0; r < 4; ++r)
                mredL[w * 64 + mt * 16 + quad * 4 + r] = lm[mt][r];
    __syncthreads();
    if (tid < 64)
        Mf[tid] = fmaxf(fmaxf(mredL[tid], mredL[64 + tid]),
                        fmaxf(mredL[128 + tid], mredL[192 + tid]));
    __syncthreads();
    // exp-sum + target extraction
    float sm[4][4];
#pragma unroll
    for (int mt = 0; mt < 4; ++mt)
#pragma unroll
        for (int r = 0; r < 4; ++r) {
            int m = mt * 16 + quad * 4 + r;
            float M = Mf[m];
            int vsg = svst[m];
            float s = 0.0f;
#pragma unroll
            for (int nt = 0; nt < 4; ++nt) {
                float lv = acc[mt][nt][r] + bb4[nt];
                s += __expf(lv - M);
                if (vbase + nt * 16 + l16 == vsg) tgt[row0 + m] = lv;
            }
            sm[mt][r] = s;
        }
#pragma unroll
    for (int o = 1; o < 16; o <<= 1)
#pragma unroll
        for (int mt = 0; mt < 4; ++mt)
#pragma unroll
            for (int r = 0; r < 4; ++r)
                sm[mt][r] += __shfl_xor(sm[mt][r], o);
    if (l16 == 0)
#pragma unroll
        for (int mt = 0; mt < 4; ++mt)
#pragma unroll
            for (int r = 0; r < 4; ++r)
                sredL[w * 64 + mt * 16 + quad * 4 + r] = sm[mt][r];
    __syncthreads();
    if (tid < 64) {
        int row = row0 + tid;
        if (row < 4128) {
            float S = sredL[tid] + sredL[64 + tid] + sredL[128 + tid] + sredL[192 + tid];
            cpm[(size_t)row * 16 + vc] = Mf[tid];
            cps[(size_t)row * 16 + vc] = S;
        }
    }
}

// ---------------- final combine + CE reduction ----------------
__global__ __launch_bounds__(256) void k_final(const float* __restrict__ cpm,
                                               const float* __restrict__ cps,
                                               const float* __restrict__ tgt,
                                               float* __restrict__ out) {
    __shared__ float red[256];
    float local = 0.0f;
    for (int r = threadIdx.x; r < 4128; r += 256) {
        float M = -1e30f;
#pragma unroll
        for (int c = 0; c < 16; ++c) M = fmaxf(M, cpm[(size_t)r * 16 + c]);
        float S = 0.0f;
#pragma unroll
        for (int c = 0; c < 16; ++c) S += cps[(size_t)r * 16 + c] * __expf(cpm[(size_t)r * 16 + c] - M);
        local += (M + logf(S)) - tgt[r];
    }
    red[threadIdx.x] = local;
    __syncthreads();
    for (int o = 128; o; o >>= 1) {
        if (threadIdx.x < o) red[threadIdx.x] += red[threadIdx.x + o];
        __syncthreads();
    }
    if (threadIdx.x == 0) out[0] = red[0] * (128.0f / 4128.0f);
}

extern "C" void kernel_launch(void* const* d_in, const int* in_sizes, int n_in,
                              void* d_out, int out_size, void* d_ws, size_t ws_size,
                              hipStream_t stream) {
    const int*   padded = (const int*)d_in[0];
    const float* enc    = (const float*)d_in[1];
    const float* emb    = (const float*)d_in[2];
    const float* W_ih0  = (const float*)d_in[3];
    const float* b_ih0  = (const float*)d_in[4];
    const float* W_hh0  = (const float*)d_in[5];
    const float* b_hh0  = (const float*)d_in[6];
    const float* W_ih1  = (const float*)d_in[7];
    const float* b_ih1  = (const float*)d_in[8];
    const float* W_hh1  = (const float*)d_in[9];
    const float* b_hh1  = (const float*)d_in[10];
    const float* W1     = (const float*)d_in[11];
    const float* b1     = (const float*)d_in[12];
    const float* W2     = (const float*)d_in[13];
    const float* b2     = (const float*)d_in[14];
    float* ws  = (float*)d_ws;
    float* out = (float*)d_out;

    hipLaunchKernelGGL(k_init, dim3(640), dim3(256), 0, stream, ws);
    hipLaunchKernelGGL(k_pack, dim3(30720), dim3(256), 0, stream,
                       W_ih0, W_hh0, W_ih1, W_hh1, W1, W2, ws);
    hipLaunchKernelGGL(k_xpre, dim3(129, 8), dim3(256), 0, stream,
                       padded, emb, (const us_t*)(ws + OFF_WXP), b_ih0, b_hh0,
                       (us_t*)(ws + OFF_XPRE));
    {
        float* ws_a = ws;
        const float* enc_a = enc;
        const float* bia = b_ih1;
        const float* bib = b_hh1;
        void* args[] = {(void*)&ws_a, (void*)&enc_a, (void*)&bia, (void*)&bib};
        hipLaunchCooperativeKernel((void*)k_seq, dim3(256), dim3(1024), args, 0, stream);
    }
    hipLaunchKernelGGL(k_mlp, dim3(129, 2), dim3(256), 0, stream,
                       (const us_t*)(ws + OFF_H1B), (const us_t*)(ws + OFF_ATB),
                       (const us_t*)(ws + OFF_W1P), b1, (us_t*)(ws + OFF_HID));
    hipLaunchKernelGGL(k_ce, dim3(65, 16), dim3(256), 0, stream,
                       (const us_t*)(ws + OFF_HID), (const us_t*)(ws + OFF_W2P), b2, padded,
                       ws + OFF_CPM, ws + OFF_CPS, ws + OFF_TGT);
    hipLaunchKernelGGL(k_final, dim3(1), dim3(256), 0, stream,
                       ws + OFF_CPM, ws + OFF_CPS, ws + OFF_TGT, out);
}